// Round 4
// baseline (868.936 us; speedup 1.0000x reference)
//
#include <hip/hip_runtime.h>
#include <hip/hip_bf16.h>
#include <hip/hip_fp16.h>

// GCN 3-layer, atomic-free hot path, fp16 storage / fp32 compute, MFMA GEMMs.
// Feature buffers are PLANE-MAJOR: plane g holds channels [16g,16g+16) for all nodes
// ([NP][N][16] fp16). Gather blocks select plane by blockIdx&7 -> round-robin XCD
// dispatch keeps each XCD's random row reads inside one L2-resident 3.2MB plane.
// CSR fill: rank captured from count's atomicAdd; fill is atomic-free + nontemporal store.

#define K_DIM 128
#define SCAN_CHUNK 1024

typedef _Float16 f16x8 __attribute__((ext_vector_type(8)));
typedef float f32x4 __attribute__((ext_vector_type(4)));
struct h2s { _Float16 x, y; };

static inline long long cdiv_ll(long long a, long long b) { return (a + b - 1) / b; }

// ---------------- CSR build ----------------
__global__ __launch_bounds__(256) void count_kernel(const int* __restrict__ col, int* __restrict__ cnt,
                                                    int* __restrict__ rank, int E) {
    int e = blockIdx.x * 256 + threadIdx.x;
    if (e < E) rank[e] = atomicAdd(&cnt[col[e]], 1);
}

__global__ __launch_bounds__(256) void dinv_kernel(const int* __restrict__ cnt, float* __restrict__ dinv, int N) {
    int n = blockIdx.x * 256 + threadIdx.x;
    if (n < N) {
        int d = cnt[n];
        dinv[n] = (d > 0) ? (1.0f / sqrtf((float)d)) : 0.0f;
    }
}

__global__ __launch_bounds__(256) void scan1_kernel(const int* __restrict__ cnt, int* __restrict__ off,
                                                    int* __restrict__ bsum, int N) {
    __shared__ int lds[256];
    const int t = threadIdx.x;
    const int base = blockIdx.x * SCAN_CHUNK;
    int v[4], s = 0;
#pragma unroll
    for (int j = 0; j < 4; ++j) {
        int i = base + t * 4 + j;
        v[j] = (i < N) ? cnt[i] : 0;
        s += v[j];
    }
    lds[t] = s;
    __syncthreads();
    for (int d = 1; d < 256; d <<= 1) {
        int x = (t >= d) ? lds[t - d] : 0;
        __syncthreads();
        lds[t] += x;
        __syncthreads();
    }
    int excl = lds[t] - s;
    if (t == 255) bsum[blockIdx.x] = lds[255];
    int run = excl;
#pragma unroll
    for (int j = 0; j < 4; ++j) {
        int i = base + t * 4 + j;
        if (i < N) off[i] = run;
        run += v[j];
    }
}

__global__ __launch_bounds__(256) void scan2_kernel(int* __restrict__ bsum, int G, int* __restrict__ off,
                                                    int N, int E) {
    __shared__ int lds[256];
    const int t = threadIdx.x;
    int s = (t < G) ? bsum[t] : 0;
    lds[t] = s;
    __syncthreads();
    for (int d = 1; d < 256; d <<= 1) {
        int x = (t >= d) ? lds[t - d] : 0;
        __syncthreads();
        lds[t] += x;
        __syncthreads();
    }
    if (t < G) bsum[t] = lds[t] - s;
    if (t == 0) off[N] = E;
}

__global__ __launch_bounds__(256) void scan3_kernel(int* __restrict__ off, const int* __restrict__ bsum, int N) {
    int add = bsum[blockIdx.x];
    const int base = blockIdx.x * SCAN_CHUNK;
#pragma unroll
    for (int j = 0; j < 4; ++j) {
        int i = base + threadIdx.x * 4 + j;
        if (i < N) off[i] += add;
    }
}

__global__ __launch_bounds__(256) void fill_kernel(const int* __restrict__ row, const int* __restrict__ col,
                                                   const int* __restrict__ off, const int* __restrict__ rank,
                                                   int* __restrict__ csr_row, int E) {
    int e = blockIdx.x * 256 + threadIdx.x;
    if (e < E) {
        int idx = off[col[e]] + rank[e];
        __builtin_nontemporal_store(row[e], &csr_row[idx]);
    }
}

// ---------------- W pack: fp32 [K][COUT] -> fp16 MFMA B-fragment order ----------------
template <int COUT>
__global__ __launch_bounds__(256) void pack_w_kernel(const float* __restrict__ W, _Float16* __restrict__ Wp) {
    constexpr int NT = COUT / 16;
    int t = blockIdx.x * 256 + threadIdx.x;
    if (t >= 4 * NT * 64) return;
    int lane = t & 63;
    int nt = (t >> 6) % NT;
    int kt = t / (64 * NT);
    int c = lane & 15, q = lane >> 4;
    f16x8 v;
#pragma unroll
    for (int j = 0; j < 8; ++j) {
        int k = kt * 32 + q * 8 + j;
        v[j] = (_Float16)W[k * COUT + nt * 16 + c];
    }
    *(f16x8*)&Wp[(size_t)t * 8] = v;
}

// ---------------- MFMA GEMM: g = dinv[n]*(A[n]@W); A fp32 row-major or fp16 plane-major;
// ---------------- output fp16 plane-major [NT][M][16] ----------------
template <int COUT, bool AF16>
__global__ __launch_bounds__(256) void gemm_mfma(const void* __restrict__ Av, const _Float16* __restrict__ Wp,
                                                 const float* __restrict__ dinv, _Float16* __restrict__ Cmat, int M) {
    constexpr int NT = COUT / 16;
    constexpr int NFRAG = 4 * NT * 64;
    __shared__ _Float16 Wlds[NFRAG * 8];

    const int t = threadIdx.x;
    for (int i = t; i < NFRAG; i += 256)
        *(f16x8*)&Wlds[(size_t)i * 8] = *(const f16x8*)&Wp[(size_t)i * 8];
    __syncthreads();

    const int lane = t & 63;
    const int wave = t >> 6;
    const int c = lane & 15;
    const int q = lane >> 4;
    const int row_base = blockIdx.x * 128 + wave * 32;

    f32x4 acc[2][NT];
#pragma unroll
    for (int rt = 0; rt < 2; ++rt)
#pragma unroll
        for (int nt = 0; nt < NT; ++nt) {
            acc[rt][nt][0] = 0.f; acc[rt][nt][1] = 0.f;
            acc[rt][nt][2] = 0.f; acc[rt][nt][3] = 0.f;
        }

#pragma unroll
    for (int kt = 0; kt < 4; ++kt) {
        f16x8 a[2];
#pragma unroll
        for (int rt = 0; rt < 2; ++rt) {
            int r = row_base + rt * 16 + c;
            r = (r < M) ? r : (M - 1);
            if (AF16) {
                const _Float16* Ap = (const _Float16*)Av;
                int p = kt * 2 + (q >> 1);
                a[rt] = *(const f16x8*)&Ap[((size_t)p * M + r) * 16 + (q & 1) * 8];
            } else {
                const float* ap = (const float*)Av + (size_t)r * K_DIM + kt * 32 + q * 8;
                float4 v0 = *(const float4*)ap;
                float4 v1 = *(const float4*)(ap + 4);
                f16x8 av;
                av[0] = (_Float16)v0.x; av[1] = (_Float16)v0.y;
                av[2] = (_Float16)v0.z; av[3] = (_Float16)v0.w;
                av[4] = (_Float16)v1.x; av[5] = (_Float16)v1.y;
                av[6] = (_Float16)v1.z; av[7] = (_Float16)v1.w;
                a[rt] = av;
            }
        }
#pragma unroll
        for (int nt = 0; nt < NT; ++nt) {
            f16x8 b = *(const f16x8*)&Wlds[(size_t)((kt * NT + nt) * 64 + lane) * 8];
            acc[0][nt] = __builtin_amdgcn_mfma_f32_16x16x32_f16(a[0], b, acc[0][nt], 0, 0, 0);
            acc[1][nt] = __builtin_amdgcn_mfma_f32_16x16x32_f16(a[1], b, acc[1][nt], 0, 0, 0);
        }
    }

#pragma unroll
    for (int rt = 0; rt < 2; ++rt)
#pragma unroll
        for (int reg = 0; reg < 4; ++reg) {
            int row = row_base + rt * 16 + q * 4 + reg;
            if (row < M) {
                float dv = dinv[row];
#pragma unroll
                for (int nt = 0; nt < NT; ++nt)
                    Cmat[((size_t)nt * M + row) * 16 + c] = (_Float16)(acc[rt][nt][reg] * dv);
            }
        }
}

// ---------------- plane-partitioned CSR gather (mid layers, 8 planes, relu, fp16 plane out) ----------------
__global__ __launch_bounds__(256) void gather_mid(const _Float16* __restrict__ g, const int* __restrict__ off,
                                                  const int* __restrict__ csr_row, const float* __restrict__ dinv,
                                                  const float* __restrict__ bias, _Float16* __restrict__ outp, int N) {
    const int gp = blockIdx.x & 7;
    const int node = (blockIdx.x >> 3) * 4 + (threadIdx.x >> 6);
    if (node >= N) return;
    const int lane = threadIdx.x & 63;
    const int es = lane >> 3;
    const int ch = lane & 7;
    const int s1 = off[node + 1];
    const _Float16* plane = g + (size_t)gp * N * 16;

    float ax = 0.f, ay = 0.f;
    for (int s = off[node] + es; s < s1; s += 8) {
        int r = csr_row[s];
        h2s v = *(const h2s*)&plane[(size_t)r * 16 + ch * 2];
        ax += (float)v.x;
        ay += (float)v.y;
    }
#pragma unroll
    for (int d = 8; d < 64; d <<= 1) {
        ax += __shfl_xor(ax, d, 64);
        ay += __shfl_xor(ay, d, 64);
    }
    if (lane < 8) {
        float dv = dinv[node];
        float ox = fmaxf(ax * dv + bias[gp * 16 + ch * 2 + 0], 0.f);
        float oy = fmaxf(ay * dv + bias[gp * 16 + ch * 2 + 1], 0.f);
        h2s o; o.x = (_Float16)ox; o.y = (_Float16)oy;
        *(h2s*)&outp[((size_t)gp * N + node) * 16 + ch * 2] = o;
    }
}

// ---------------- final gather (4 planes, no relu, fp32 row-major out) ----------------
__global__ __launch_bounds__(256) void gather_final(const _Float16* __restrict__ g, const int* __restrict__ off,
                                                    const int* __restrict__ csr_row, const float* __restrict__ dinv,
                                                    const float* __restrict__ bias, float* __restrict__ out, int N) {
    const int gp = blockIdx.x & 3;
    const int node = (blockIdx.x >> 2) * 4 + (threadIdx.x >> 6);
    if (node >= N) return;
    const int lane = threadIdx.x & 63;
    const int es = lane >> 3;
    const int ch = lane & 7;
    const int s1 = off[node + 1];
    const _Float16* plane = g + (size_t)gp * N * 16;

    float ax = 0.f, ay = 0.f;
    for (int s = off[node] + es; s < s1; s += 8) {
        int r = csr_row[s];
        h2s v = *(const h2s*)&plane[(size_t)r * 16 + ch * 2];
        ax += (float)v.x;
        ay += (float)v.y;
    }
#pragma unroll
    for (int d = 8; d < 64; d <<= 1) {
        ax += __shfl_xor(ax, d, 64);
        ay += __shfl_xor(ay, d, 64);
    }
    if (lane < 8) {
        float dv = dinv[node];
        float2 o;
        o.x = ax * dv + bias[gp * 16 + ch * 2 + 0];
        o.y = ay * dv + bias[gp * 16 + ch * 2 + 1];
        *(float2*)&out[(size_t)node * 64 + gp * 16 + ch * 2] = o;
    }
}

extern "C" void kernel_launch(void* const* d_in, const int* in_sizes, int n_in,
                              void* d_out, int out_size, void* d_ws, size_t ws_size,
                              hipStream_t stream) {
    const float* x  = (const float*)d_in[0];
    const int*   ei = (const int*)d_in[1];
    const float* W1 = (const float*)d_in[2];
    const float* b1 = (const float*)d_in[3];
    const float* W2 = (const float*)d_in[4];
    const float* b2 = (const float*)d_in[5];
    const float* W3 = (const float*)d_in[6];
    const float* b3 = (const float*)d_in[7];

    const int N = in_sizes[0] / 128;   // 100000
    const int E = in_sizes[1] / 2;     // 1600000
    const int* row = ei;
    const int* col = ei + E;
    const int G = (int)cdiv_ll(N, SCAN_CHUNK);

    // workspace layout
    char* wsb = (char*)d_ws;
    int*      cnt     = (int*)wsb;      wsb += (size_t)N * 4;
    float*    dinv    = (float*)wsb;    wsb += (size_t)N * 4;
    int*      off     = (int*)wsb;      wsb += (size_t)(N + 1) * 4;
    int*      bsum    = (int*)wsb;      wsb += 256 * 4;
    int*      rank    = (int*)wsb;      wsb += (size_t)E * 4;
    int*      csr_row = (int*)wsb;      wsb += (size_t)E * 4;
    wsb = (char*)((((uintptr_t)wsb) + 15) & ~(uintptr_t)15);
    _Float16* Wp1     = (_Float16*)wsb; wsb += 16384 * 2;
    _Float16* Wp2     = (_Float16*)wsb; wsb += 16384 * 2;
    _Float16* Wp3     = (_Float16*)wsb; wsb += 8192 * 2;
    _Float16* bufA    = (_Float16*)wsb; wsb += (size_t)N * 128 * 2;   // plane-major [8][N][16]
    _Float16* bufB    = (_Float16*)wsb;                               // plane-major
    float*    out     = (float*)d_out;

    // ---- CSR build + dinv + W pack ----
    hipMemsetAsync(cnt, 0, (size_t)N * 4, stream);
    count_kernel<<<cdiv_ll(E, 256), 256, 0, stream>>>(col, cnt, rank, E);
    dinv_kernel<<<cdiv_ll(N, 256), 256, 0, stream>>>(cnt, dinv, N);
    scan1_kernel<<<G, 256, 0, stream>>>(cnt, off, bsum, N);
    scan2_kernel<<<1, 256, 0, stream>>>(bsum, G, off, N, E);
    scan3_kernel<<<G, 256, 0, stream>>>(off, bsum, N);
    fill_kernel<<<cdiv_ll(E, 256), 256, 0, stream>>>(row, col, off, rank, csr_row, E);
    pack_w_kernel<128><<<8, 256, 0, stream>>>(W1, Wp1);
    pack_w_kernel<128><<<8, 256, 0, stream>>>(W2, Wp2);
    pack_w_kernel<64><<<4, 256, 0, stream>>>(W3, Wp3);

    const long long gemmBlocks  = cdiv_ll(N, 128);
    const long long gMidBlocks  = cdiv_ll(N, 4) * 8;
    const long long gFinBlocks  = cdiv_ll(N, 4) * 4;

    // ---- layer 1 ----
    gemm_mfma<128, false><<<gemmBlocks, 256, 0, stream>>>(x, Wp1, dinv, bufA, N);
    gather_mid<<<gMidBlocks, 256, 0, stream>>>(bufA, off, csr_row, dinv, b1, bufB, N);

    // ---- layer 2 ----
    gemm_mfma<128, true><<<gemmBlocks, 256, 0, stream>>>(bufB, Wp2, dinv, bufA, N);
    gather_mid<<<gMidBlocks, 256, 0, stream>>>(bufA, off, csr_row, dinv, b2, bufB, N);

    // ---- layer 3 ----
    gemm_mfma<64, true><<<gemmBlocks, 256, 0, stream>>>(bufB, Wp3, dinv, bufA, N);
    gather_final<<<gFinBlocks, 256, 0, stream>>>(bufA, off, csr_row, dinv, b3, out, N);
}

// Round 5
// 492.249 us; speedup vs baseline: 1.7652x; 1.7652x over previous
//
#include <hip/hip_runtime.h>
#include <hip/hip_bf16.h>
#include <hip/hip_fp16.h>

// GCN 3-layer, atomic-free hot path, fp16 storage / fp32 compute, MFMA GEMMs.
// Feature buffers PLANE-MAJOR: plane g = channels [16g,16g+16) for all nodes
// ([NP][N][16] fp16). Gather: block = 32 nodes x 1 plane; chunk of 512 edges
// staged into LDS by all 256 threads (high MLP), then thread=(node,2ch)
// accumulates from LDS (no global latency, no shuffles). blockIdx%NP -> plane
// keeps each XCD's feature reads in one L2-resident 3.2MB plane.

#define K_DIM 128
#define SCAN_CHUNK 1024

typedef _Float16 f16x8 __attribute__((ext_vector_type(8)));
typedef float f32x4 __attribute__((ext_vector_type(4)));
struct h2s { _Float16 x, y; };

static inline long long cdiv_ll(long long a, long long b) { return (a + b - 1) / b; }

// ---------------- CSR build ----------------
__global__ __launch_bounds__(256) void count_kernel(const int* __restrict__ col, int* __restrict__ cnt,
                                                    int* __restrict__ rank, int E) {
    int e = blockIdx.x * 256 + threadIdx.x;
    if (e < E) rank[e] = atomicAdd(&cnt[col[e]], 1);
}

__global__ __launch_bounds__(256) void dinv_kernel(const int* __restrict__ cnt, float* __restrict__ dinv, int N) {
    int n = blockIdx.x * 256 + threadIdx.x;
    if (n < N) {
        int d = cnt[n];
        dinv[n] = (d > 0) ? (1.0f / sqrtf((float)d)) : 0.0f;
    }
}

__global__ __launch_bounds__(256) void scan1_kernel(const int* __restrict__ cnt, int* __restrict__ off,
                                                    int* __restrict__ bsum, int N) {
    __shared__ int lds[256];
    const int t = threadIdx.x;
    const int base = blockIdx.x * SCAN_CHUNK;
    int v[4], s = 0;
#pragma unroll
    for (int j = 0; j < 4; ++j) {
        int i = base + t * 4 + j;
        v[j] = (i < N) ? cnt[i] : 0;
        s += v[j];
    }
    lds[t] = s;
    __syncthreads();
    for (int d = 1; d < 256; d <<= 1) {
        int x = (t >= d) ? lds[t - d] : 0;
        __syncthreads();
        lds[t] += x;
        __syncthreads();
    }
    int excl = lds[t] - s;
    if (t == 255) bsum[blockIdx.x] = lds[255];
    int run = excl;
#pragma unroll
    for (int j = 0; j < 4; ++j) {
        int i = base + t * 4 + j;
        if (i < N) off[i] = run;
        run += v[j];
    }
}

__global__ __launch_bounds__(256) void scan2_kernel(int* __restrict__ bsum, int G, int* __restrict__ off,
                                                    int N, int E) {
    __shared__ int lds[256];
    const int t = threadIdx.x;
    int s = (t < G) ? bsum[t] : 0;
    lds[t] = s;
    __syncthreads();
    for (int d = 1; d < 256; d <<= 1) {
        int x = (t >= d) ? lds[t - d] : 0;
        __syncthreads();
        lds[t] += x;
        __syncthreads();
    }
    if (t < G) bsum[t] = lds[t] - s;
    if (t == 0) off[N] = E;
}

__global__ __launch_bounds__(256) void scan3_kernel(int* __restrict__ off, const int* __restrict__ bsum, int N) {
    int add = bsum[blockIdx.x];
    const int base = blockIdx.x * SCAN_CHUNK;
#pragma unroll
    for (int j = 0; j < 4; ++j) {
        int i = base + threadIdx.x * 4 + j;
        if (i < N) off[i] += add;
    }
}

__global__ __launch_bounds__(256) void fill_kernel(const int* __restrict__ row, const int* __restrict__ col,
                                                   const int* __restrict__ off, const int* __restrict__ rank,
                                                   int* __restrict__ csr_row, int E) {
    int e = blockIdx.x * 256 + threadIdx.x;
    if (e < E) {
        int idx = off[col[e]] + rank[e];
        __builtin_nontemporal_store(row[e], &csr_row[idx]);
    }
}

// ---------------- W pack: fp32 [K][COUT] -> fp16 MFMA B-fragment order ----------------
template <int COUT>
__global__ __launch_bounds__(256) void pack_w_kernel(const float* __restrict__ W, _Float16* __restrict__ Wp) {
    constexpr int NT = COUT / 16;
    int t = blockIdx.x * 256 + threadIdx.x;
    if (t >= 4 * NT * 64) return;
    int lane = t & 63;
    int nt = (t >> 6) % NT;
    int kt = t / (64 * NT);
    int c = lane & 15, q = lane >> 4;
    f16x8 v;
#pragma unroll
    for (int j = 0; j < 8; ++j) {
        int k = kt * 32 + q * 8 + j;
        v[j] = (_Float16)W[k * COUT + nt * 16 + c];
    }
    *(f16x8*)&Wp[(size_t)t * 8] = v;
}

// ---------------- MFMA GEMM: g = dinv[n]*(A[n]@W); A fp32 row-major or fp16 plane-major;
// ---------------- output fp16 plane-major [NT][M][16] ----------------
template <int COUT, bool AF16>
__global__ __launch_bounds__(256) void gemm_mfma(const void* __restrict__ Av, const _Float16* __restrict__ Wp,
                                                 const float* __restrict__ dinv, _Float16* __restrict__ Cmat, int M) {
    constexpr int NT = COUT / 16;
    constexpr int NFRAG = 4 * NT * 64;
    __shared__ _Float16 Wlds[NFRAG * 8];

    const int t = threadIdx.x;
    for (int i = t; i < NFRAG; i += 256)
        *(f16x8*)&Wlds[(size_t)i * 8] = *(const f16x8*)&Wp[(size_t)i * 8];
    __syncthreads();

    const int lane = t & 63;
    const int wave = t >> 6;
    const int c = lane & 15;
    const int q = lane >> 4;
    const int row_base = blockIdx.x * 128 + wave * 32;

    f32x4 acc[2][NT];
#pragma unroll
    for (int rt = 0; rt < 2; ++rt)
#pragma unroll
        for (int nt = 0; nt < NT; ++nt) {
            acc[rt][nt][0] = 0.f; acc[rt][nt][1] = 0.f;
            acc[rt][nt][2] = 0.f; acc[rt][nt][3] = 0.f;
        }

#pragma unroll
    for (int kt = 0; kt < 4; ++kt) {
        f16x8 a[2];
#pragma unroll
        for (int rt = 0; rt < 2; ++rt) {
            int r = row_base + rt * 16 + c;
            r = (r < M) ? r : (M - 1);
            if (AF16) {
                const _Float16* Ap = (const _Float16*)Av;
                int p = kt * 2 + (q >> 1);
                a[rt] = *(const f16x8*)&Ap[((size_t)p * M + r) * 16 + (q & 1) * 8];
            } else {
                const float* ap = (const float*)Av + (size_t)r * K_DIM + kt * 32 + q * 8;
                float4 v0 = *(const float4*)ap;
                float4 v1 = *(const float4*)(ap + 4);
                f16x8 av;
                av[0] = (_Float16)v0.x; av[1] = (_Float16)v0.y;
                av[2] = (_Float16)v0.z; av[3] = (_Float16)v0.w;
                av[4] = (_Float16)v1.x; av[5] = (_Float16)v1.y;
                av[6] = (_Float16)v1.z; av[7] = (_Float16)v1.w;
                a[rt] = av;
            }
        }
#pragma unroll
        for (int nt = 0; nt < NT; ++nt) {
            f16x8 b = *(const f16x8*)&Wlds[(size_t)((kt * NT + nt) * 64 + lane) * 8];
            acc[0][nt] = __builtin_amdgcn_mfma_f32_16x16x32_f16(a[0], b, acc[0][nt], 0, 0, 0);
            acc[1][nt] = __builtin_amdgcn_mfma_f32_16x16x32_f16(a[1], b, acc[1][nt], 0, 0, 0);
        }
    }

#pragma unroll
    for (int rt = 0; rt < 2; ++rt)
#pragma unroll
        for (int reg = 0; reg < 4; ++reg) {
            int row = row_base + rt * 16 + q * 4 + reg;
            if (row < M) {
                float dv = dinv[row];
#pragma unroll
                for (int nt = 0; nt < NT; ++nt)
                    Cmat[((size_t)nt * M + row) * 16 + c] = (_Float16)(acc[rt][nt][reg] * dv);
            }
        }
}

// ---------------- LDS-staged plane gather ----------------
// block = 32 nodes x 1 plane; 512-edge chunks staged to LDS by all 256 threads,
// then thread=(node, 2ch) accumulates from LDS. out mid: fp16 plane-major;
// out final: fp32 row-major.
template <int NP, bool RELU, typename OutT>
__global__ __launch_bounds__(256) void gather_lds(const _Float16* __restrict__ g, const int* __restrict__ off,
                                                  const int* __restrict__ csr_row, const float* __restrict__ dinv,
                                                  const float* __restrict__ bias, OutT* __restrict__ outp, int N) {
    constexpr int NTILE = 32;
    constexpr int CH = 512;
    __shared__ _Float16 feat[CH * 16];   // 32B rows, 16B-aligned
    __shared__ int off_s[NTILE + 1];

    const int t = threadIdx.x;
    const int plane = blockIdx.x % NP;
    const int node0 = (blockIdx.x / NP) * NTILE;
    const _Float16* gp = g + (size_t)plane * N * 16;

    if (t <= NTILE) {
        int idx = node0 + t;
        off_s[t] = off[idx < N ? idx : N];
    }
    __syncthreads();

    const int n_loc = t >> 3;            // node within tile (0..31)
    const int q = t & 7;                 // channel pair (2 ch each)
    const int node = node0 + n_loc;
    const bool valid = node < N;
    const int sn0 = off_s[n_loc];
    const int sn1 = off_s[n_loc + 1];
    const int s_begin = off_s[0];
    const int s_end = off_s[NTILE];

    float ax = 0.f, ay = 0.f;

    for (int cs = s_begin; cs < s_end; cs += CH) {
        const int ce = (cs + CH < s_end) ? (cs + CH) : s_end;
        const int cnt = ce - cs;
        // phase 1: stage chunk's feature rows into LDS (dense, independent loads)
        for (int i = t; i < cnt; i += 256) {
            int r = csr_row[cs + i];
            const _Float16* src = gp + (size_t)r * 16;
            f16x8 lo = *(const f16x8*)src;
            f16x8 hi = *(const f16x8*)(src + 8);
            *(f16x8*)&feat[i * 16] = lo;
            *(f16x8*)&feat[i * 16 + 8] = hi;
        }
        __syncthreads();
        // phase 2: accumulate this node's edges within the chunk from LDS
        const int lo_s = (sn0 > cs) ? sn0 : cs;
        const int hi_s = (sn1 < ce) ? sn1 : ce;
        for (int s = lo_s; s < hi_s; ++s) {
            h2s v = *(const h2s*)&feat[(s - cs) * 16 + q * 2];
            ax += (float)v.x;
            ay += (float)v.y;
        }
        __syncthreads();
    }

    if (valid) {
        float dv = dinv[node];
        float ox = ax * dv + bias[plane * 16 + q * 2 + 0];
        float oy = ay * dv + bias[plane * 16 + q * 2 + 1];
        if (RELU) { ox = fmaxf(ox, 0.f); oy = fmaxf(oy, 0.f); }
        if constexpr (sizeof(OutT) == 2) {
            h2s o; o.x = (_Float16)ox; o.y = (_Float16)oy;
            *(h2s*)((_Float16*)outp + ((size_t)plane * N + node) * 16 + q * 2) = o;
        } else {
            float2 o = make_float2(ox, oy);
            *(float2*)((float*)outp + (size_t)node * 64 + plane * 16 + q * 2) = o;
        }
    }
}

extern "C" void kernel_launch(void* const* d_in, const int* in_sizes, int n_in,
                              void* d_out, int out_size, void* d_ws, size_t ws_size,
                              hipStream_t stream) {
    const float* x  = (const float*)d_in[0];
    const int*   ei = (const int*)d_in[1];
    const float* W1 = (const float*)d_in[2];
    const float* b1 = (const float*)d_in[3];
    const float* W2 = (const float*)d_in[4];
    const float* b2 = (const float*)d_in[5];
    const float* W3 = (const float*)d_in[6];
    const float* b3 = (const float*)d_in[7];

    const int N = in_sizes[0] / 128;   // 100000
    const int E = in_sizes[1] / 2;     // 1600000
    const int* row = ei;
    const int* col = ei + E;
    const int G = (int)cdiv_ll(N, SCAN_CHUNK);

    // workspace layout
    char* wsb = (char*)d_ws;
    int*      cnt     = (int*)wsb;      wsb += (size_t)N * 4;
    float*    dinv    = (float*)wsb;    wsb += (size_t)N * 4;
    int*      off     = (int*)wsb;      wsb += (size_t)(N + 1) * 4;
    int*      bsum    = (int*)wsb;      wsb += 256 * 4;
    int*      rank    = (int*)wsb;      wsb += (size_t)E * 4;
    int*      csr_row = (int*)wsb;      wsb += (size_t)E * 4;
    wsb = (char*)((((uintptr_t)wsb) + 15) & ~(uintptr_t)15);
    _Float16* Wp1     = (_Float16*)wsb; wsb += 16384 * 2;
    _Float16* Wp2     = (_Float16*)wsb; wsb += 16384 * 2;
    _Float16* Wp3     = (_Float16*)wsb; wsb += 8192 * 2;
    _Float16* bufA    = (_Float16*)wsb; wsb += (size_t)N * 128 * 2;   // plane-major [8][N][16]
    _Float16* bufB    = (_Float16*)wsb;                               // plane-major
    float*    out     = (float*)d_out;

    // ---- CSR build + dinv + W pack ----
    hipMemsetAsync(cnt, 0, (size_t)N * 4, stream);
    count_kernel<<<cdiv_ll(E, 256), 256, 0, stream>>>(col, cnt, rank, E);
    dinv_kernel<<<cdiv_ll(N, 256), 256, 0, stream>>>(cnt, dinv, N);
    scan1_kernel<<<G, 256, 0, stream>>>(cnt, off, bsum, N);
    scan2_kernel<<<1, 256, 0, stream>>>(bsum, G, off, N, E);
    scan3_kernel<<<G, 256, 0, stream>>>(off, bsum, N);
    fill_kernel<<<cdiv_ll(E, 256), 256, 0, stream>>>(row, col, off, rank, csr_row, E);
    pack_w_kernel<128><<<8, 256, 0, stream>>>(W1, Wp1);
    pack_w_kernel<128><<<8, 256, 0, stream>>>(W2, Wp2);
    pack_w_kernel<64><<<4, 256, 0, stream>>>(W3, Wp3);

    const long long gemmBlocks = cdiv_ll(N, 128);
    const long long nb         = cdiv_ll(N, 32);

    // ---- layer 1 ----
    gemm_mfma<128, false><<<gemmBlocks, 256, 0, stream>>>(x, Wp1, dinv, bufA, N);
    gather_lds<8, true, _Float16><<<nb * 8, 256, 0, stream>>>(bufA, off, csr_row, dinv, b1, bufB, N);

    // ---- layer 2 ----
    gemm_mfma<128, true><<<gemmBlocks, 256, 0, stream>>>(bufB, Wp2, dinv, bufA, N);
    gather_lds<8, true, _Float16><<<nb * 8, 256, 0, stream>>>(bufA, off, csr_row, dinv, b2, bufB, N);

    // ---- layer 3 ----
    gemm_mfma<64, true><<<gemmBlocks, 256, 0, stream>>>(bufB, Wp3, dinv, bufA, N);
    gather_lds<4, false, float><<<nb * 4, 256, 0, stream>>>(bufA, off, csr_row, dinv, b3, out, N);
}